// Round 16
// baseline (252.299 us; speedup 1.0000x reference)
//
#include <hip/hip_runtime.h>
#include <hip/hip_bf16.h>
#include <stdint.h>

// SingleHeadAttention: B=8 T=2048 E=1024 A=1024, fp32 in/out, bf16 MFMA inside.
// Round 16 = R15 (244.8us) with ONE change: pv rebuilt at 256-wide d-tiles
// (256 blocks, 8 waves, wave-grid 2q x 4d, per-wave 64x64 acc[4][4] -- per-wave
// MFMA chain unchanged vs R12 pv). Per-CU staged-ksub count halves (68 -> 34);
// the 128^2 body's cost is ~0.9us/ksub/CU (stage-latency dominated), so fewer
// fatter ksubs win. prep / qkv_qk / score_v = R15 verbatim.

#define BB 8
#define TT 2048
#define EE 1024
#define AA 1024
#define MM (BB * TT)  // 16384

typedef short bf16x8 __attribute__((ext_vector_type(8)));
typedef float f32x4 __attribute__((ext_vector_type(4)));

#define GLOAD_LDS16(g, l)                                                      \
  __builtin_amdgcn_global_load_lds(                                            \
      (const __attribute__((address_space(1))) void*)(g),                      \
      (__attribute__((address_space(3))) void*)(l), 16, 0, 0)

#define SBAR()                               \
  do {                                       \
    __builtin_amdgcn_sched_barrier(0);       \
    __builtin_amdgcn_s_barrier();            \
    __builtin_amdgcn_sched_barrier(0);       \
  } while (0)

#define LGKM0()                                          \
  do {                                                   \
    asm volatile("s_waitcnt lgkmcnt(0)" ::: "memory");   \
    __builtin_amdgcn_sched_barrier(0);                   \
  } while (0)

#define VMCNT(n)                                              \
  do {                                                        \
    asm volatile("s_waitcnt vmcnt(" #n ")" ::: "memory");     \
    __builtin_amdgcn_sched_barrier(0);                        \
  } while (0)

// ---------------------------------------------------------------------------
// R9 256x256x(K) bt-GEMM core: uniform 1-region/phase staging, vmcnt(6).
// ---------------------------------------------------------------------------
__device__ __forceinline__ void gemm256_core(
    const short* __restrict__ gA, int lda, int a0row,
    const short* __restrict__ gB, int ldb, int b0row, int NT, short* As,
    short* Bs, f32x4 (*acc)[4]) {
  const int tid = threadIdx.x;
  const int lane = tid & 63;
  const int w = tid >> 6;
  const int wr = w >> 2, wc = w & 3;
  const int lrow = lane & 15;
  const int lk8 = (lane >> 4) * 8;
  const int swz = ((lrow >> 3) & 1) << 4;
  const int baseA = (((wr * 128 + lrow) * 32) + lk8) ^ swz;
  const int baseB = (((wc * 64 + lrow) * 32) + lk8) ^ swz;

  const short* pA[2];
  const short* pB[2];
  int dL[2];
#pragma unroll
  for (int i = 0; i < 2; ++i) {
    int chunk = 2 * w + i;
    int P = chunk * 1024 + lane * 16;           // phys byte in 16KB region
    int L = P ^ (((P >> 9) & 1) << 5);          // logical byte
    int row = L >> 6;
    int kb2 = (L & 63) >> 1;                    // shorts
    pA[i] = gA + (size_t)(a0row + row) * lda + kb2;
    pB[i] = gB + (size_t)(b0row + row) * ldb + kb2;
    dL[i] = chunk * 512 + lane * 8;
  }

#define STG_A(tl, s)                                                           \
  do {                                                                         \
    int _o = (tl) * 64 + (s) * 32;                                             \
    short* _d = As + (((tl) & 1) << 14) + ((s) << 13);                         \
    GLOAD_LDS16(pA[0] + _o, _d + dL[0]);                                       \
    GLOAD_LDS16(pA[1] + _o, _d + dL[1]);                                       \
  } while (0)
#define STG_B(tl, s)                                                           \
  do {                                                                         \
    int _o = (tl) * 64 + (s) * 32;                                             \
    short* _d = Bs + (((tl) & 1) << 14) + ((s) << 13);                         \
    GLOAD_LDS16(pB[0] + _o, _d + dL[0]);                                       \
    GLOAD_LDS16(pB[1] + _o, _d + dL[1]);                                       \
  } while (0)

  STG_B(0, 0); STG_A(0, 0); STG_B(0, 1); STG_A(0, 1);
  if (NT > 1) {
    STG_B(1, 0); STG_A(1, 0); STG_A(1, 1);
    VMCNT(6);
  } else {
    VMCNT(0);
  }
  SBAR();

  for (int t = 0; t < NT; ++t) {
    short* Ac = As + (t & 1) * 16384;
    short* Bc = Bs + (t & 1) * 16384;
    const bool stg = (t < NT - 2);
    bf16x8 a0[4], a1[4], a2[4], a3[4], b0[4], b1[4];

    // ph0: read A m0-3/kk0 + B kk0; stage B-k1(t+1)
#pragma unroll
    for (int m = 0; m < 4; ++m) a0[m] = *(const bf16x8*)&Ac[baseA + m * 512];
#pragma unroll
    for (int n = 0; n < 4; ++n) b0[n] = *(const bf16x8*)&Bc[baseB + n * 512];
    if (t < NT - 1) STG_B(t + 1, 1);
    SBAR();
    LGKM0();
    __builtin_amdgcn_s_setprio(1);
#pragma unroll
    for (int m = 0; m < 4; ++m)
#pragma unroll
      for (int n = 0; n < 4; ++n)
        acc[m][n] = __builtin_amdgcn_mfma_f32_16x16x32_bf16(a0[m], b0[n],
                                                            acc[m][n], 0, 0, 0);
    __builtin_amdgcn_s_setprio(0);
    SBAR();

    // ph1: read A m4-7/kk0 + A m0-3/kk1; stage B-k0(t+2)
#pragma unroll
    for (int m = 0; m < 4; ++m)
      a1[m] = *(const bf16x8*)&Ac[baseA + (m + 4) * 512];
#pragma unroll
    for (int m = 0; m < 4; ++m)
      a2[m] = *(const bf16x8*)&Ac[8192 + baseA + m * 512];
    if (stg) STG_B(t + 2, 0);
    SBAR();
    LGKM0();
    __builtin_amdgcn_s_setprio(1);
#pragma unroll
    for (int m = 0; m < 4; ++m)
#pragma unroll
      for (int n = 0; n < 4; ++n)
        acc[m + 4][n] = __builtin_amdgcn_mfma_f32_16x16x32_bf16(
            a1[m], b0[n], acc[m + 4][n], 0, 0, 0);
    __builtin_amdgcn_s_setprio(0);
    SBAR();

    // ph2: read A m4-7/kk1 + B kk1; stage A-k0(t+2)
#pragma unroll
    for (int m = 0; m < 4; ++m)
      a3[m] = *(const bf16x8*)&Ac[8192 + baseA + (m + 4) * 512];
#pragma unroll
    for (int n = 0; n < 4; ++n)
      b1[n] = *(const bf16x8*)&Bc[8192 + baseB + n * 512];
    if (stg) STG_A(t + 2, 0);
    SBAR();
    LGKM0();
    __builtin_amdgcn_s_setprio(1);
#pragma unroll
    for (int m = 0; m < 4; ++m)
#pragma unroll
      for (int n = 0; n < 4; ++n)
        acc[m][n] = __builtin_amdgcn_mfma_f32_16x16x32_bf16(a2[m], b1[n],
                                                            acc[m][n], 0, 0, 0);
    __builtin_amdgcn_s_setprio(0);
    SBAR();

    // ph3: stage A-k1(t+2); boundary vmcnt(6)
    if (stg) {
      STG_A(t + 2, 1);
      VMCNT(6);
    } else if (t == NT - 2) {
      VMCNT(0);
    }
    SBAR();
    __builtin_amdgcn_s_setprio(1);
#pragma unroll
    for (int m = 0; m < 4; ++m)
#pragma unroll
      for (int n = 0; n < 4; ++n)
        acc[m + 4][n] = __builtin_amdgcn_mfma_f32_16x16x32_bf16(
            a3[m], b1[n], acc[m + 4][n], 0, 0, 0);
    __builtin_amdgcn_s_setprio(0);
    SBAR();
  }
#undef STG_A
#undef STG_B
}

// ---------------------------------------------------------------------------
// R1-style 128x128 helpers (diag tail) — 4-wave.
// ---------------------------------------------------------------------------
__device__ __forceinline__ void stage_tile(const short* __restrict__ g,
                                           size_t stride, short* lds, int tid) {
#pragma unroll
  for (int r = 0; r < 4; ++r) {
    int t = r * 256 + tid;
    int row = t >> 3;
    int c = (t & 7) * 8;
    GLOAD_LDS16(g + (size_t)row * stride + c, lds + (size_t)t * 8);
  }
}

// Generic MFMA step over [*][64] LDS tiles; wave (wr,wc) covers rows
// wr*64.. (A) x wc*64.. (B), acc[4][4] = 64x64 out.
__device__ __forceinline__ void mfma_step(const short* As, const short* Bs,
                                          f32x4 acc[4][4], int lane, int wr,
                                          int wc) {
  int lrow = lane & 15;
  int lk = (lane >> 4) * 8;
#pragma unroll
  for (int kk = 0; kk < 64; kk += 32) {
    bf16x8 a[4], b[4];
#pragma unroll
    for (int i = 0; i < 4; ++i)
      a[i] = *(const bf16x8*)&As[(wr * 64 + i * 16 + lrow) * 64 + kk + lk];
#pragma unroll
    for (int j = 0; j < 4; ++j)
      b[j] = *(const bf16x8*)&Bs[(wc * 64 + j * 16 + lrow) * 64 + kk + lk];
#pragma unroll
    for (int i = 0; i < 4; ++i)
#pragma unroll
      for (int j = 0; j < 4; ++j)
        acc[i][j] =
            __builtin_amdgcn_mfma_f32_16x16x32_bf16(a[i], b[j], acc[i][j], 0, 0, 0);
  }
}

// ---------------------------------------------------------------------------
// qkv_qk: Q and K projections only. grid 512 x 512thr. (R15 verbatim)
// ---------------------------------------------------------------------------
__global__ __launch_bounds__(512, 2) void qkv_qk(
    const short* __restrict__ xb, const short* __restrict__ Wb,
    short* __restrict__ qk) {
  __shared__ __align__(16) short SH[65536];
  short* As = SH;
  short* Bs = SH + 32768;
  int f = blockIdx.x;
  int s = (f & 7) * 64 + (f >> 3);
  int mt = s >> 3;
  int rem = s & 7;
  int z = rem >> 2, ntl = rem & 3;
  const short* gB = Wb + (size_t)z * AA * EE + (size_t)(ntl * 256) * EE;
  f32x4 acc[8][4];
#pragma unroll
  for (int m = 0; m < 8; ++m)
#pragma unroll
    for (int n = 0; n < 4; ++n) acc[m][n] = (f32x4){0.f, 0.f, 0.f, 0.f};
  gemm256_core(xb, EE, mt * 256, gB, EE, 0, EE / 64, As, Bs, acc);

  int tid = threadIdx.x;
  int lane = tid & 63, w = tid >> 6, wr = w >> 2, wc = w & 3;
  int lrow = lane & 15, lk4 = (lane >> 4) * 4;
  short* o = qk + (size_t)z * MM * AA;
  int row0 = mt * 256 + wr * 128;
  int col0 = ntl * 256 + wc * 64;
#pragma unroll
  for (int m = 0; m < 8; ++m)
#pragma unroll
    for (int n = 0; n < 4; ++n)
#pragma unroll
      for (int r = 0; r < 4; ++r) {
        int row = row0 + m * 16 + lk4 + r;
        int col = col0 + n * 16 + lrow;
        __hip_bfloat16 h = __float2bfloat16(acc[m][n][r]);
        o[(size_t)row * AA + col] = *(short*)&h;
      }
}

// ---------------------------------------------------------------------------
// score_v: grid 480 x 512thr. (R15 verbatim)
//   f < 224: score supertile (+ diag tail, j<24).
//   f >= 224: V projection block + fused V-transpose -> Vt.
// ---------------------------------------------------------------------------
__global__ __launch_bounds__(512, 2) void score_v(
    const short* __restrict__ xb, const short* __restrict__ Wb,
    const short* __restrict__ Qb, const short* __restrict__ Kb,
    short* __restrict__ Pu, float* __restrict__ lsum,
    short* __restrict__ Vt) {
  __shared__ __align__(16) short SH[65536];
  short* As = SH;
  short* Bs = SH + 32768;
  int f = blockIdx.x;
  int tid = threadIdx.x;
  int lane = tid & 63, w = tid >> 6, wr8 = w >> 2, wc8 = w & 3;
  int lrow = lane & 15, lk4 = (lane >> 4) * 4;
  const float scale = 0.03125f;  // 1/sqrt(1024)

  if (f < 224) {
    int b = f & 7;
    int j = f >> 3;  // [0,28)
    int MT = 1;
    while ((MT + 1) * MT / 2 <= j) ++MT;
    int NT = j - MT * (MT - 1) / 2;  // NT < MT
    const short* Q = Qb + (size_t)b * TT * AA;
    const short* K = Kb + (size_t)b * TT * AA;
    short* P = Pu + (size_t)b * TT * TT;

    {
      f32x4 acc[8][4];
#pragma unroll
      for (int m = 0; m < 8; ++m)
#pragma unroll
        for (int n = 0; n < 4; ++n) acc[m][n] = (f32x4){0.f, 0.f, 0.f, 0.f};
      gemm256_core(Q, AA, MT * 256, K, AA, NT * 256, AA / 64, As, Bs, acc);

      int q0 = MT * 256 + wr8 * 128;
      int c0 = NT * 256 + wc8 * 64;
#pragma unroll
      for (int m = 0; m < 8; ++m) {
#pragma unroll
        for (int r = 0; r < 4; ++r) {
          int q = q0 + m * 16 + lk4 + r;
          float rs = 0.f;
#pragma unroll
          for (int n = 0; n < 4; ++n) {
            int kx = c0 + n * 16 + lrow;
            float e = __expf(acc[m][n][r] * scale);  // kx < q always
            rs += e;
            __hip_bfloat16 h = __float2bfloat16(e);
            P[(size_t)q * TT + kx] = *(short*)&h;
          }
          rs += __shfl_xor(rs, 1);
          rs += __shfl_xor(rs, 2);
          rs += __shfl_xor(rs, 4);
          rs += __shfl_xor(rs, 8);
          if (lrow == 0) atomicAdd(&lsum[b * TT + q], rs);
        }
      }
    }

    // diag tail: blocks j<24, one 128^2 subtile, 4-wave body (tid<256 guard).
    if (j < 24) {
      int M = j / 3, r3 = j - 3 * M;
      int mt = 2 * M + (r3 > 0);
      int nt = 2 * M + (r3 == 2);
      int q0 = mt * 128, c0 = nt * 128;
      bool act = tid < 256;
      int wid4 = (tid >> 6) & 3, wr = wid4 >> 1, wc = wid4 & 1;

      f32x4 acc[4][4];
#pragma unroll
      for (int i = 0; i < 4; ++i)
#pragma unroll
        for (int jj = 0; jj < 4; ++jj) acc[i][jj] = (f32x4){0.f, 0.f, 0.f, 0.f};

      __syncthreads();
      for (int k0 = 0; k0 < AA; k0 += 64) {
        if (act) {
          stage_tile(Q + (size_t)q0 * AA + k0, AA, As, tid);
          stage_tile(K + (size_t)c0 * AA + k0, AA, Bs, tid);
        }
        __syncthreads();
        if (act) mfma_step(As, Bs, acc, lane, wr, wc);
        __syncthreads();
      }
      if (act) {
#pragma unroll
        for (int i = 0; i < 4; ++i) {
#pragma unroll
          for (int r = 0; r < 4; ++r) {
            int q = q0 + wr * 64 + i * 16 + lk4 + r;
            float rs = 0.f;
#pragma unroll
            for (int jj = 0; jj < 4; ++jj) {
              int kx = c0 + wc * 64 + jj * 16 + lrow;
              float e = (kx <= q) ? __expf(acc[i][jj][r] * scale) : 0.f;
              rs += e;
              __hip_bfloat16 h = __float2bfloat16(e);
              P[(size_t)q * TT + kx] = *(short*)&h;
            }
            rs += __shfl_xor(rs, 1);
            rs += __shfl_xor(rs, 2);
            rs += __shfl_xor(rs, 4);
            rs += __shfl_xor(rs, 8);
            if (lrow == 0) atomicAdd(&lsum[b * TT + q], rs);
          }
        }
      }
    }
  } else {
    // ---- V projection block: X . Wv^T tile + fused transpose -> Vt.
    int g = f - 224;                       // [0,256)
    int s2 = (g & 7) * 32 + (g >> 3);      // XCD x gets mt band [x*8, x*8+8)
    int mt = s2 >> 2, ntl = s2 & 3;
    const short* gB = Wb + (size_t)2 * AA * EE + (size_t)(ntl * 256) * EE;
    f32x4 acc[8][4];
#pragma unroll
    for (int m = 0; m < 8; ++m)
#pragma unroll
      for (int n = 0; n < 4; ++n) acc[m][n] = (f32x4){0.f, 0.f, 0.f, 0.f};
    gemm256_core(xb, EE, mt * 256, gB, EE, 0, EE / 64, As, Bs, acc);

    __syncthreads();
    int lr0 = wr8 * 128, lc0 = wc8 * 64;
#pragma unroll
    for (int m = 0; m < 8; ++m)
#pragma unroll
      for (int n = 0; n < 4; ++n)
#pragma unroll
        for (int r = 0; r < 4; ++r) {
          int lr = lr0 + m * 16 + lk4 + r;
          int lc = lc0 + n * 16 + lrow;
          __hip_bfloat16 h = __float2bfloat16(acc[m][n][r]);
          SH[lc * 256 + (lr ^ ((lc & 7) << 3))] = *(short*)&h;
        }
    __syncthreads();
    int row0 = mt * 256;
    int bq = row0 >> 11;        // tile never straddles a batch (2048%256==0)
    int t0 = row0 & 2047;
#pragma unroll
    for (int pass = 0; pass < 4; ++pass) {
      int lc = pass * 64 + (tid >> 3);
      int d = ntl * 256 + lc;
      size_t dst = ((size_t)bq * AA + d) * TT + t0;
      int sw = (lc & 7) << 3;
#pragma unroll
      for (int gg = 0; gg < 4; ++gg) {
        int lr = (tid & 7) * 8 + gg * 64;
        bf16x8 vv = *(const bf16x8*)&SH[lc * 256 + (lr ^ sw)];
        *(bf16x8*)&Vt[dst + lr] = vv;
      }
    }
  }
}

// ---------------------------------------------------------------------------
// PV 256d: grid 256 (8 b x 8 pp x 4 nt), 8 waves / 512 thr. Wave grid 2q x 4d,
// per-wave 64x64 out (acc[4][4], MFMA chain per ksub unchanged vs R12 pv).
// Two-pass balanced pairing (strips pp and 15-pp). LDS = P 16KB + V 32KB.
// ---------------------------------------------------------------------------
__global__ __launch_bounds__(512) void pv_gemm(const short* __restrict__ Pu,
                                               const short* __restrict__ Vt,
                                               const float* __restrict__ lsum,
                                               float* __restrict__ out) {
  int f = blockIdx.x;
  int b = f & 7;
  int j = f >> 3;          // [0,32)
  int pp = j >> 2;         // [0,8)
  int nt = j & 3;          // [0,4)
  int n0 = nt * 256;

  __shared__ __align__(16) short Ps[128 * 64];  // 16 KB
  __shared__ __align__(16) short Vs[256 * 64];  // 32 KB
  int tid = threadIdx.x;
  int lane = tid & 63, w = tid >> 6, wq = w >> 2, wd = w & 3;
  const short* P = Pu + (size_t)b * TT * TT;
  const short* V = Vt + (size_t)b * AA * TT;
  int lrow = lane & 15, lk4 = (lane >> 4) * 4;

#pragma unroll
  for (int s = 0; s < 2; ++s) {
    int mt = s ? (15 - pp) : pp;
    int q0 = mt * 128;
    f32x4 acc[4][4];
#pragma unroll
    for (int i = 0; i < 4; ++i)
#pragma unroll
      for (int jj = 0; jj < 4; ++jj) acc[i][jj] = (f32x4){0.f, 0.f, 0.f, 0.f};

    int kend = q0 + 128;
    for (int k0 = 0; k0 < kend; k0 += 64) {
      // stage P [128][64]: 2 x 512thr x 16B
#pragma unroll
      for (int r = 0; r < 2; ++r) {
        int t = r * 512 + tid;
        int row = t >> 3;
        int c = (t & 7) * 8;
        GLOAD_LDS16(P + (size_t)(q0 + row) * TT + k0 + c, Ps + (size_t)t * 8);
      }
      // stage V [256][64]: 4 x 512thr x 16B
#pragma unroll
      for (int r = 0; r < 4; ++r) {
        int t = r * 512 + tid;
        int row = t >> 3;
        int c = (t & 7) * 8;
        GLOAD_LDS16(V + (size_t)(n0 + row) * TT + k0 + c, Vs + (size_t)t * 8);
      }
      __syncthreads();
      mfma_step(Ps, Vs, acc, lane, wq, wd);
      __syncthreads();
    }
#pragma unroll
    for (int i = 0; i < 4; ++i) {
#pragma unroll
      for (int r = 0; r < 4; ++r) {
        int q = q0 + wq * 64 + i * 16 + lk4 + r;
        float linv = 1.0f / lsum[b * TT + q];
#pragma unroll
        for (int jj = 0; jj < 4; ++jj) {
          int d = n0 + wd * 64 + jj * 16 + lrow;
          out[((size_t)(b * TT + q)) * AA + d] = acc[i][jj][r] * linv;
        }
      }
    }
  }
}

// ---------------------------------------------------------------------------
// prep: X -> bf16, [Wq|Wk|Wv] -> bf16, Ls = 0. One launch. (R15 verbatim)
// ---------------------------------------------------------------------------
__global__ void prep(const float* __restrict__ x, const float* __restrict__ wq,
                     const float* __restrict__ wk, const float* __restrict__ wv,
                     short* __restrict__ Xb, short* __restrict__ Wb,
                     float* __restrict__ Ls) {
  const int nx4 = MM * EE / 4;
  const int nw4 = AA * EE / 4;
  int gid = blockIdx.x * blockDim.x + threadIdx.x;
  if (gid < MM) Ls[gid] = 0.f;
  int stride = gridDim.x * blockDim.x;
  for (int i = gid; i < nx4 + 3 * nw4; i += stride) {
    const float* src;
    short* dst;
    int ii;
    if (i < nx4) {
      src = x; dst = Xb; ii = i;
    } else {
      int j = i - nx4;
      int z = j / nw4;
      ii = j - z * nw4;
      src = (z == 0) ? wq : (z == 1 ? wk : wv);
      dst = Wb + (size_t)z * AA * EE;
    }
    float4 v = ((const float4*)src)[ii];
    __hip_bfloat16 h0 = __float2bfloat16(v.x);
    __hip_bfloat16 h1 = __float2bfloat16(v.y);
    __hip_bfloat16 h2 = __float2bfloat16(v.z);
    __hip_bfloat16 h3 = __float2bfloat16(v.w);
    short4 o;
    o.x = *(short*)&h0;
    o.y = *(short*)&h1;
    o.z = *(short*)&h2;
    o.w = *(short*)&h3;
    ((short4*)dst)[ii] = o;
  }
}

extern "C" void kernel_launch(void* const* d_in, const int* in_sizes, int n_in,
                              void* d_out, int out_size, void* d_ws,
                              size_t ws_size, hipStream_t stream) {
  const float* x = (const float*)d_in[0];
  const float* Wq = (const float*)d_in[1];
  const float* Wk = (const float*)d_in[2];
  const float* Wv = (const float*)d_in[3];

  char* ws = (char*)d_ws;
  size_t oWb = 0;
  size_t oQb = oWb + (size_t)3 * AA * EE * 2;   // 6 MB
  size_t oKb = oQb + (size_t)MM * AA * 2;
  size_t oVt = oKb + (size_t)MM * AA * 2;
  size_t oLs = oVt + (size_t)MM * AA * 2;
  size_t oXb = oLs + (size_t)MM * 4;
  size_t oPu = oXb + (size_t)MM * EE * 2;  // Xb stays live through score_v

  short* Wb = (short*)(ws + oWb);
  short* Qb = (short*)(ws + oQb);
  short* Kb = (short*)(ws + oKb);
  short* Vt = (short*)(ws + oVt);
  float* Ls = (float*)(ws + oLs);
  short* Xb = (short*)(ws + oXb);
  short* Pu = (short*)(ws + oPu);

  prep<<<2048, 256, 0, stream>>>(x, Wq, Wk, Wv, Xb, Wb, Ls);

  qkv_qk<<<512, 512, 0, stream>>>(Xb, Wb, Qb);
  score_v<<<480, 512, 0, stream>>>(Xb, Wb, Qb, Kb, Pu, Ls, Vt);
  pv_gemm<<<256, 512, 0, stream>>>(Pu, Vt, Ls, (float*)d_out);
}

// Round 17
// 243.226 us; speedup vs baseline: 1.0373x; 1.0373x over previous
//
#include <hip/hip_runtime.h>
#include <hip/hip_bf16.h>
#include <stdint.h>

// SingleHeadAttention: B=8 T=2048 E=1024 A=1024, fp32 in/out, bf16 MFMA inside.
// Round 17 = R15 verbatim (measured best, 244.8us). R16's 256-wide pv reverted
// per pre-commit (fatter ksubs lost ~7us: extra staged bytes + 4 serial V-stage
// rounds outweighed the halved ksub count).
// Structure: prep -> qkv_qk (512 blk, Q+K) -> score_v (480 blk = 224 score
// supertile+diag + 256 V-GEMM w/ fused transpose) -> pv (4-wave, balanced
// p/15-p pairing). Pu does NOT alias Xb (Xb live through score_v).

#define BB 8
#define TT 2048
#define EE 1024
#define AA 1024
#define MM (BB * TT)  // 16384

typedef short bf16x8 __attribute__((ext_vector_type(8)));
typedef float f32x4 __attribute__((ext_vector_type(4)));

#define GLOAD_LDS16(g, l)                                                      \
  __builtin_amdgcn_global_load_lds(                                            \
      (const __attribute__((address_space(1))) void*)(g),                      \
      (__attribute__((address_space(3))) void*)(l), 16, 0, 0)

#define SBAR()                               \
  do {                                       \
    __builtin_amdgcn_sched_barrier(0);       \
    __builtin_amdgcn_s_barrier();            \
    __builtin_amdgcn_sched_barrier(0);       \
  } while (0)

#define LGKM0()                                          \
  do {                                                   \
    asm volatile("s_waitcnt lgkmcnt(0)" ::: "memory");   \
    __builtin_amdgcn_sched_barrier(0);                   \
  } while (0)

#define VMCNT(n)                                              \
  do {                                                        \
    asm volatile("s_waitcnt vmcnt(" #n ")" ::: "memory");     \
    __builtin_amdgcn_sched_barrier(0);                        \
  } while (0)

// ---------------------------------------------------------------------------
// R9 256x256x(K) bt-GEMM core: uniform 1-region/phase staging, vmcnt(6).
// ---------------------------------------------------------------------------
__device__ __forceinline__ void gemm256_core(
    const short* __restrict__ gA, int lda, int a0row,
    const short* __restrict__ gB, int ldb, int b0row, int NT, short* As,
    short* Bs, f32x4 (*acc)[4]) {
  const int tid = threadIdx.x;
  const int lane = tid & 63;
  const int w = tid >> 6;
  const int wr = w >> 2, wc = w & 3;
  const int lrow = lane & 15;
  const int lk8 = (lane >> 4) * 8;
  const int swz = ((lrow >> 3) & 1) << 4;
  const int baseA = (((wr * 128 + lrow) * 32) + lk8) ^ swz;
  const int baseB = (((wc * 64 + lrow) * 32) + lk8) ^ swz;

  const short* pA[2];
  const short* pB[2];
  int dL[2];
#pragma unroll
  for (int i = 0; i < 2; ++i) {
    int chunk = 2 * w + i;
    int P = chunk * 1024 + lane * 16;           // phys byte in 16KB region
    int L = P ^ (((P >> 9) & 1) << 5);          // logical byte
    int row = L >> 6;
    int kb2 = (L & 63) >> 1;                    // shorts
    pA[i] = gA + (size_t)(a0row + row) * lda + kb2;
    pB[i] = gB + (size_t)(b0row + row) * ldb + kb2;
    dL[i] = chunk * 512 + lane * 8;
  }

#define STG_A(tl, s)                                                           \
  do {                                                                         \
    int _o = (tl) * 64 + (s) * 32;                                             \
    short* _d = As + (((tl) & 1) << 14) + ((s) << 13);                         \
    GLOAD_LDS16(pA[0] + _o, _d + dL[0]);                                       \
    GLOAD_LDS16(pA[1] + _o, _d + dL[1]);                                       \
  } while (0)
#define STG_B(tl, s)                                                           \
  do {                                                                         \
    int _o = (tl) * 64 + (s) * 32;                                             \
    short* _d = Bs + (((tl) & 1) << 14) + ((s) << 13);                         \
    GLOAD_LDS16(pB[0] + _o, _d + dL[0]);                                       \
    GLOAD_LDS16(pB[1] + _o, _d + dL[1]);                                       \
  } while (0)

  STG_B(0, 0); STG_A(0, 0); STG_B(0, 1); STG_A(0, 1);
  if (NT > 1) {
    STG_B(1, 0); STG_A(1, 0); STG_A(1, 1);
    VMCNT(6);
  } else {
    VMCNT(0);
  }
  SBAR();

  for (int t = 0; t < NT; ++t) {
    short* Ac = As + (t & 1) * 16384;
    short* Bc = Bs + (t & 1) * 16384;
    const bool stg = (t < NT - 2);
    bf16x8 a0[4], a1[4], a2[4], a3[4], b0[4], b1[4];

    // ph0: read A m0-3/kk0 + B kk0; stage B-k1(t+1)
#pragma unroll
    for (int m = 0; m < 4; ++m) a0[m] = *(const bf16x8*)&Ac[baseA + m * 512];
#pragma unroll
    for (int n = 0; n < 4; ++n) b0[n] = *(const bf16x8*)&Bc[baseB + n * 512];
    if (t < NT - 1) STG_B(t + 1, 1);
    SBAR();
    LGKM0();
    __builtin_amdgcn_s_setprio(1);
#pragma unroll
    for (int m = 0; m < 4; ++m)
#pragma unroll
      for (int n = 0; n < 4; ++n)
        acc[m][n] = __builtin_amdgcn_mfma_f32_16x16x32_bf16(a0[m], b0[n],
                                                            acc[m][n], 0, 0, 0);
    __builtin_amdgcn_s_setprio(0);
    SBAR();

    // ph1: read A m4-7/kk0 + A m0-3/kk1; stage B-k0(t+2)
#pragma unroll
    for (int m = 0; m < 4; ++m)
      a1[m] = *(const bf16x8*)&Ac[baseA + (m + 4) * 512];
#pragma unroll
    for (int m = 0; m < 4; ++m)
      a2[m] = *(const bf16x8*)&Ac[8192 + baseA + m * 512];
    if (stg) STG_B(t + 2, 0);
    SBAR();
    LGKM0();
    __builtin_amdgcn_s_setprio(1);
#pragma unroll
    for (int m = 0; m < 4; ++m)
#pragma unroll
      for (int n = 0; n < 4; ++n)
        acc[m + 4][n] = __builtin_amdgcn_mfma_f32_16x16x32_bf16(
            a1[m], b0[n], acc[m + 4][n], 0, 0, 0);
    __builtin_amdgcn_s_setprio(0);
    SBAR();

    // ph2: read A m4-7/kk1 + B kk1; stage A-k0(t+2)
#pragma unroll
    for (int m = 0; m < 4; ++m)
      a3[m] = *(const bf16x8*)&Ac[8192 + baseA + (m + 4) * 512];
#pragma unroll
    for (int n = 0; n < 4; ++n)
      b1[n] = *(const bf16x8*)&Bc[8192 + baseB + n * 512];
    if (stg) STG_A(t + 2, 0);
    SBAR();
    LGKM0();
    __builtin_amdgcn_s_setprio(1);
#pragma unroll
    for (int m = 0; m < 4; ++m)
#pragma unroll
      for (int n = 0; n < 4; ++n)
        acc[m][n] = __builtin_amdgcn_mfma_f32_16x16x32_bf16(a2[m], b1[n],
                                                            acc[m][n], 0, 0, 0);
    __builtin_amdgcn_s_setprio(0);
    SBAR();

    // ph3: stage A-k1(t+2); boundary vmcnt(6)
    if (stg) {
      STG_A(t + 2, 1);
      VMCNT(6);
    } else if (t == NT - 2) {
      VMCNT(0);
    }
    SBAR();
    __builtin_amdgcn_s_setprio(1);
#pragma unroll
    for (int m = 0; m < 4; ++m)
#pragma unroll
      for (int n = 0; n < 4; ++n)
        acc[m + 4][n] = __builtin_amdgcn_mfma_f32_16x16x32_bf16(
            a3[m], b1[n], acc[m + 4][n], 0, 0, 0);
    __builtin_amdgcn_s_setprio(0);
    SBAR();
  }
#undef STG_A
#undef STG_B
}

// ---------------------------------------------------------------------------
// R1-style 128x128 helpers (diag tail + pv) — 4-wave.
// ---------------------------------------------------------------------------
__device__ __forceinline__ void stage_tile(const short* __restrict__ g,
                                           size_t stride, short* lds, int tid) {
#pragma unroll
  for (int r = 0; r < 4; ++r) {
    int t = r * 256 + tid;
    int row = t >> 3;
    int c = (t & 7) * 8;
    GLOAD_LDS16(g + (size_t)row * stride + c, lds + (size_t)t * 8);
  }
}

__device__ __forceinline__ void mfma_step(const short* As, const short* Bs,
                                          f32x4 acc[4][4], int lane, int wr,
                                          int wc) {
  int lrow = lane & 15;
  int lk = (lane >> 4) * 8;
#pragma unroll
  for (int kk = 0; kk < 64; kk += 32) {
    bf16x8 a[4], b[4];
#pragma unroll
    for (int i = 0; i < 4; ++i)
      a[i] = *(const bf16x8*)&As[(wr * 64 + i * 16 + lrow) * 64 + kk + lk];
#pragma unroll
    for (int j = 0; j < 4; ++j)
      b[j] = *(const bf16x8*)&Bs[(wc * 64 + j * 16 + lrow) * 64 + kk + lk];
#pragma unroll
    for (int i = 0; i < 4; ++i)
#pragma unroll
      for (int j = 0; j < 4; ++j)
        acc[i][j] =
            __builtin_amdgcn_mfma_f32_16x16x32_bf16(a[i], b[j], acc[i][j], 0, 0, 0);
  }
}

// ---------------------------------------------------------------------------
// qkv_qk: Q and K projections only. grid 512 x 512thr.
// ---------------------------------------------------------------------------
__global__ __launch_bounds__(512, 2) void qkv_qk(
    const short* __restrict__ xb, const short* __restrict__ Wb,
    short* __restrict__ qk) {
  __shared__ __align__(16) short SH[65536];
  short* As = SH;
  short* Bs = SH + 32768;
  int f = blockIdx.x;
  int s = (f & 7) * 64 + (f >> 3);
  int mt = s >> 3;
  int rem = s & 7;
  int z = rem >> 2, ntl = rem & 3;
  const short* gB = Wb + (size_t)z * AA * EE + (size_t)(ntl * 256) * EE;
  f32x4 acc[8][4];
#pragma unroll
  for (int m = 0; m < 8; ++m)
#pragma unroll
    for (int n = 0; n < 4; ++n) acc[m][n] = (f32x4){0.f, 0.f, 0.f, 0.f};
  gemm256_core(xb, EE, mt * 256, gB, EE, 0, EE / 64, As, Bs, acc);

  int tid = threadIdx.x;
  int lane = tid & 63, w = tid >> 6, wr = w >> 2, wc = w & 3;
  int lrow = lane & 15, lk4 = (lane >> 4) * 4;
  short* o = qk + (size_t)z * MM * AA;
  int row0 = mt * 256 + wr * 128;
  int col0 = ntl * 256 + wc * 64;
#pragma unroll
  for (int m = 0; m < 8; ++m)
#pragma unroll
    for (int n = 0; n < 4; ++n)
#pragma unroll
      for (int r = 0; r < 4; ++r) {
        int row = row0 + m * 16 + lk4 + r;
        int col = col0 + n * 16 + lrow;
        __hip_bfloat16 h = __float2bfloat16(acc[m][n][r]);
        o[(size_t)row * AA + col] = *(short*)&h;
      }
}

// ---------------------------------------------------------------------------
// score_v: grid 480 x 512thr.
//   f < 224: score supertile (+ diag tail, j<24).
//   f >= 224: V projection block + fused V-transpose -> Vt.
// ---------------------------------------------------------------------------
__global__ __launch_bounds__(512, 2) void score_v(
    const short* __restrict__ xb, const short* __restrict__ Wb,
    const short* __restrict__ Qb, const short* __restrict__ Kb,
    short* __restrict__ Pu, float* __restrict__ lsum,
    short* __restrict__ Vt) {
  __shared__ __align__(16) short SH[65536];
  short* As = SH;
  short* Bs = SH + 32768;
  int f = blockIdx.x;
  int tid = threadIdx.x;
  int lane = tid & 63, w = tid >> 6, wr8 = w >> 2, wc8 = w & 3;
  int lrow = lane & 15, lk4 = (lane >> 4) * 4;
  const float scale = 0.03125f;  // 1/sqrt(1024)

  if (f < 224) {
    int b = f & 7;
    int j = f >> 3;  // [0,28)
    int MT = 1;
    while ((MT + 1) * MT / 2 <= j) ++MT;
    int NT = j - MT * (MT - 1) / 2;  // NT < MT
    const short* Q = Qb + (size_t)b * TT * AA;
    const short* K = Kb + (size_t)b * TT * AA;
    short* P = Pu + (size_t)b * TT * TT;

    {
      f32x4 acc[8][4];
#pragma unroll
      for (int m = 0; m < 8; ++m)
#pragma unroll
        for (int n = 0; n < 4; ++n) acc[m][n] = (f32x4){0.f, 0.f, 0.f, 0.f};
      gemm256_core(Q, AA, MT * 256, K, AA, NT * 256, AA / 64, As, Bs, acc);

      int q0 = MT * 256 + wr8 * 128;
      int c0 = NT * 256 + wc8 * 64;
#pragma unroll
      for (int m = 0; m < 8; ++m) {
#pragma unroll
        for (int r = 0; r < 4; ++r) {
          int q = q0 + m * 16 + lk4 + r;
          float rs = 0.f;
#pragma unroll
          for (int n = 0; n < 4; ++n) {
            int kx = c0 + n * 16 + lrow;
            float e = __expf(acc[m][n][r] * scale);  // kx < q always
            rs += e;
            __hip_bfloat16 h = __float2bfloat16(e);
            P[(size_t)q * TT + kx] = *(short*)&h;
          }
          rs += __shfl_xor(rs, 1);
          rs += __shfl_xor(rs, 2);
          rs += __shfl_xor(rs, 4);
          rs += __shfl_xor(rs, 8);
          if (lrow == 0) atomicAdd(&lsum[b * TT + q], rs);
        }
      }
    }

    // diag tail: blocks j<24, one 128^2 subtile, 4-wave body (tid<256 guard).
    if (j < 24) {
      int M = j / 3, r3 = j - 3 * M;
      int mt = 2 * M + (r3 > 0);
      int nt = 2 * M + (r3 == 2);
      int q0 = mt * 128, c0 = nt * 128;
      bool act = tid < 256;
      int wid4 = (tid >> 6) & 3, wr = wid4 >> 1, wc = wid4 & 1;

      f32x4 acc[4][4];
#pragma unroll
      for (int i = 0; i < 4; ++i)
#pragma unroll
        for (int jj = 0; jj < 4; ++jj) acc[i][jj] = (f32x4){0.f, 0.f, 0.f, 0.f};

      __syncthreads();
      for (int k0 = 0; k0 < AA; k0 += 64) {
        if (act) {
          stage_tile(Q + (size_t)q0 * AA + k0, AA, As, tid);
          stage_tile(K + (size_t)c0 * AA + k0, AA, Bs, tid);
        }
        __syncthreads();
        if (act) mfma_step(As, Bs, acc, lane, wr, wc);
        __syncthreads();
      }
      if (act) {
#pragma unroll
        for (int i = 0; i < 4; ++i) {
#pragma unroll
          for (int r = 0; r < 4; ++r) {
            int q = q0 + wr * 64 + i * 16 + lk4 + r;
            float rs = 0.f;
#pragma unroll
            for (int jj = 0; jj < 4; ++jj) {
              int kx = c0 + wc * 64 + jj * 16 + lrow;
              float e = (kx <= q) ? __expf(acc[i][jj][r] * scale) : 0.f;
              rs += e;
              __hip_bfloat16 h = __float2bfloat16(e);
              P[(size_t)q * TT + kx] = *(short*)&h;
            }
            rs += __shfl_xor(rs, 1);
            rs += __shfl_xor(rs, 2);
            rs += __shfl_xor(rs, 4);
            rs += __shfl_xor(rs, 8);
            if (lrow == 0) atomicAdd(&lsum[b * TT + q], rs);
          }
        }
      }
    }
  } else {
    // ---- V projection block: X . Wv^T tile + fused transpose -> Vt.
    int g = f - 224;                       // [0,256)
    int s2 = (g & 7) * 32 + (g >> 3);      // XCD x gets mt band [x*8, x*8+8)
    int mt = s2 >> 2, ntl = s2 & 3;
    const short* gB = Wb + (size_t)2 * AA * EE + (size_t)(ntl * 256) * EE;
    f32x4 acc[8][4];
#pragma unroll
    for (int m = 0; m < 8; ++m)
#pragma unroll
      for (int n = 0; n < 4; ++n) acc[m][n] = (f32x4){0.f, 0.f, 0.f, 0.f};
    gemm256_core(xb, EE, mt * 256, gB, EE, 0, EE / 64, As, Bs, acc);

    __syncthreads();
    int lr0 = wr8 * 128, lc0 = wc8 * 64;
#pragma unroll
    for (int m = 0; m < 8; ++m)
#pragma unroll
      for (int n = 0; n < 4; ++n)
#pragma unroll
        for (int r = 0; r < 4; ++r) {
          int lr = lr0 + m * 16 + lk4 + r;
          int lc = lc0 + n * 16 + lrow;
          __hip_bfloat16 h = __float2bfloat16(acc[m][n][r]);
          SH[lc * 256 + (lr ^ ((lc & 7) << 3))] = *(short*)&h;
        }
    __syncthreads();
    int row0 = mt * 256;
    int bq = row0 >> 11;        // tile never straddles a batch (2048%256==0)
    int t0 = row0 & 2047;
#pragma unroll
    for (int pass = 0; pass < 4; ++pass) {
      int lc = pass * 64 + (tid >> 3);
      int d = ntl * 256 + lc;
      size_t dst = ((size_t)bq * AA + d) * TT + t0;
      int sw = (lc & 7) << 3;
#pragma unroll
      for (int gg = 0; gg < 4; ++gg) {
        int lr = (tid & 7) * 8 + gg * 64;
        bf16x8 vv = *(const bf16x8*)&SH[lc * 256 + (lr ^ sw)];
        *(bf16x8*)&Vt[dst + lr] = vv;
      }
    }
  }
}

// ---------------------------------------------------------------------------
// PV (R12 4-wave): balanced pairing, block handles q-strips p and 15-p.
// grid 512 (8 b x 8 p x 8 nt).
// ---------------------------------------------------------------------------
__global__ __launch_bounds__(256) void pv_gemm(const short* __restrict__ Pu,
                                               const short* __restrict__ Vt,
                                               const float* __restrict__ lsum,
                                               float* __restrict__ out) {
  int f = blockIdx.x;
  int b = f & 7;
  int j = f >> 3;          // [0,64)
  int p = j >> 3;          // [0,8)
  int nt = j & 7;
  int n0 = nt * 128;

  __shared__ __align__(16) short As[128 * 64];
  __shared__ __align__(16) short Bs[128 * 64];
  int tid = threadIdx.x;
  int lane = tid & 63, wid = tid >> 6, wr = wid >> 1, wc = wid & 1;
  const short* P = Pu + (size_t)b * TT * TT;
  const short* V = Vt + (size_t)b * AA * TT;
  int lrow = lane & 15, lk4 = (lane >> 4) * 4;

#pragma unroll
  for (int s = 0; s < 2; ++s) {
    int mt = s ? (15 - p) : p;
    int q0 = mt * 128;
    f32x4 acc[4][4];
#pragma unroll
    for (int i = 0; i < 4; ++i)
#pragma unroll
      for (int jj = 0; jj < 4; ++jj) acc[i][jj] = (f32x4){0.f, 0.f, 0.f, 0.f};

    int kend = q0 + 128;
    for (int k0 = 0; k0 < kend; k0 += 64) {
      stage_tile(P + (size_t)q0 * TT + k0, TT, As, tid);
      stage_tile(V + (size_t)n0 * TT + k0, TT, Bs, tid);
      __syncthreads();
      mfma_step(As, Bs, acc, lane, wr, wc);
      __syncthreads();
    }
#pragma unroll
    for (int i = 0; i < 4; ++i) {
#pragma unroll
      for (int r = 0; r < 4; ++r) {
        int q = q0 + wr * 64 + i * 16 + lk4 + r;
        float linv = 1.0f / lsum[b * TT + q];
#pragma unroll
        for (int jj = 0; jj < 4; ++jj) {
          int d = n0 + wc * 64 + jj * 16 + lrow;
          out[((size_t)(b * TT + q)) * AA + d] = acc[i][jj][r] * linv;
        }
      }
    }
  }
}

// ---------------------------------------------------------------------------
// prep: X -> bf16, [Wq|Wk|Wv] -> bf16, Ls = 0. One launch.
// ---------------------------------------------------------------------------
__global__ void prep(const float* __restrict__ x, const float* __restrict__ wq,
                     const float* __restrict__ wk, const float* __restrict__ wv,
                     short* __restrict__ Xb, short* __restrict__ Wb,
                     float* __restrict__ Ls) {
  const int nx4 = MM * EE / 4;
  const int nw4 = AA * EE / 4;
  int gid = blockIdx.x * blockDim.x + threadIdx.x;
  if (gid < MM) Ls[gid] = 0.f;
  int stride = gridDim.x * blockDim.x;
  for (int i = gid; i < nx4 + 3 * nw4; i += stride) {
    const float* src;
    short* dst;
    int ii;
    if (i < nx4) {
      src = x; dst = Xb; ii = i;
    } else {
      int j = i - nx4;
      int z = j / nw4;
      ii = j - z * nw4;
      src = (z == 0) ? wq : (z == 1 ? wk : wv);
      dst = Wb + (size_t)z * AA * EE;
    }
    float4 v = ((const float4*)src)[ii];
    __hip_bfloat16 h0 = __float2bfloat16(v.x);
    __hip_bfloat16 h1 = __float2bfloat16(v.y);
    __hip_bfloat16 h2 = __float2bfloat16(v.z);
    __hip_bfloat16 h3 = __float2bfloat16(v.w);
    short4 o;
    o.x = *(short*)&h0;
    o.y = *(short*)&h1;
    o.z = *(short*)&h2;
    o.w = *(short*)&h3;
    ((short4*)dst)[ii] = o;
  }
}

extern "C" void kernel_launch(void* const* d_in, const int* in_sizes, int n_in,
                              void* d_out, int out_size, void* d_ws,
                              size_t ws_size, hipStream_t stream) {
  const float* x = (const float*)d_in[0];
  const float* Wq = (const float*)d_in[1];
  const float* Wk = (const float*)d_in[2];
  const float* Wv = (const float*)d_in[3];

  char* ws = (char*)d_ws;
  size_t oWb = 0;
  size_t oQb = oWb + (size_t)3 * AA * EE * 2;   // 6 MB
  size_t oKb = oQb + (size_t)MM * AA * 2;
  size_t oVt = oKb + (size_t)MM * AA * 2;
  size_t oLs = oVt + (size_t)MM * AA * 2;
  size_t oXb = oLs + (size_t)MM * 4;
  size_t oPu = oXb + (size_t)MM * EE * 2;  // Pu does NOT alias Xb
                                           // (Xb live through score_v)

  short* Wb = (short*)(ws + oWb);
  short* Qb = (short*)(ws + oQb);
  short* Kb = (short*)(ws + oKb);
  short* Vt = (short*)(ws + oVt);
  float* Ls = (float*)(ws + oLs);
  short* Xb = (short*)(ws + oXb);
  short* Pu = (short*)(ws + oPu);

  prep<<<2048, 256, 0, stream>>>(x, Wq, Wk, Wv, Xb, Wb, Ls);

  qkv_qk<<<512, 512, 0, stream>>>(Xb, Wb, Qb);
  score_v<<<480, 512, 0, stream>>>(Xb, Wb, Qb, Kb, Pu, Ls, Vt);
  pv_gemm<<<512, 256, 0, stream>>>(Pu, Vt, Ls, (float*)d_out);
}